// Round 15
// baseline (156.189 us; speedup 1.0000x reference)
//
#include <hip/hip_runtime.h>

#define NN 100000
#define NE 1250000
#define DIM 64

#define BSHIFT 8                                   // 256 nodes per bucket
#define BNODES (1 << BSHIFT)
#define NBUCK ((NN + BNODES - 1) / BNODES)         // 391
#define BIN_BLOCKS 256
#define BIN_CHUNK ((NE + BIN_BLOCKS - 1) / BIN_BLOCKS)  // 4883
#define BCAP 4096                                  // fixed per-bucket capacity (avg 3200, ~15 sigma headroom)

typedef unsigned short bf16_t;
typedef __attribute__((ext_vector_type(8))) short short8;
typedef __attribute__((ext_vector_type(8))) unsigned short ushort8;
typedef __attribute__((ext_vector_type(4))) float f32x4;

static __device__ __forceinline__ bf16_t f2bf(float f) {
    union { float f; unsigned int u; } c; c.f = f;
    unsigned int u = c.u;
    u += 0x7FFFu + ((u >> 16) & 1u);          // RNE
    return (bf16_t)(u >> 16);
}
static __device__ __forceinline__ float bf2f(bf16_t b) {
    union { unsigned int u; float f; } c; c.u = ((unsigned int)b) << 16;
    return c.f;
}

union ABFrag { short8 v; short s[8]; };

// ==================== linear via MFMA: h = x @ W^T (+fused scores) ====================
// one wave per 16 rows; 512-thread blocks = 8 waves = 128 rows per tile.
template<bool IN_BF16, bool RELU_IN>
static __device__ __forceinline__
void linear_body(int bid, const void* __restrict__ xin,
                 const float* __restrict__ W,
                 const float* __restrict__ a_src,
                 const float* __restrict__ a_dst,
                 bf16_t* __restrict__ h,
                 float* __restrict__ s_src,
                 float* __restrict__ s_dst)
{
    int tid  = threadIdx.x;
    int lane = tid & 63;
    int wid  = tid >> 6;     // 0..7
    int lr   = lane & 15;    // A-row / B,D-col (mod 16)
    int lg   = lane >> 4;    // k-group / D-row-group
    int rowbase = bid * 128 + wid * 16;

    // ---- B fragments from W (L2-hot, 16 KB) ----
    ABFrag Bf[4][2];
#pragma unroll
    for (int t = 0; t < 4; ++t)
#pragma unroll
    for (int s = 0; s < 2; ++s) {
        const f32x4* wp = reinterpret_cast<const f32x4*>(W + (lr + 16*t)*DIM + 32*s + 8*lg);
        f32x4 w0 = wp[0], w1 = wp[1];
#pragma unroll
        for (int j = 0; j < 4; ++j) {
            Bf[t][s].s[j]     = (short)f2bf(w0[j]);
            Bf[t][s].s[j + 4] = (short)f2bf(w1[j]);
        }
    }

    int arow = rowbase + lr;
    if (arow > NN - 1) arow = NN - 1;        // tail clamp; invalid D-rows masked at store

    // ---- A fragments ----
    ABFrag Af[2];
    if (IN_BF16) {
        const bf16_t* xp = (const bf16_t*)xin + (size_t)arow * DIM + 8*lg;
#pragma unroll
        for (int s = 0; s < 2; ++s) {
            ushort8 xv = *reinterpret_cast<const ushort8*>(xp + 32*s);
#pragma unroll
            for (int j = 0; j < 8; ++j) {
                unsigned short b = xv[j];
                if (RELU_IN) b = (b & 0x8000u) ? (unsigned short)0 : b;   // relu on bf16 bits
                Af[s].s[j] = (short)b;
            }
        }
    } else {
        const float* xp = (const float*)xin + (size_t)arow * DIM + 8*lg;
#pragma unroll
        for (int s = 0; s < 2; ++s) {
            const f32x4* xq = reinterpret_cast<const f32x4*>(xp + 32*s);
            f32x4 x0 = xq[0], x1 = xq[1];
#pragma unroll
            for (int j = 0; j < 4; ++j) {
                float f0 = x0[j], f1 = x1[j];
                if (RELU_IN) { f0 = f0 > 0.f ? f0 : 0.f; f1 = f1 > 0.f ? f1 : 0.f; }
                Af[s].s[j]     = (short)f2bf(f0);
                Af[s].s[j + 4] = (short)f2bf(f1);
            }
        }
    }

    // ---- 8 MFMAs ----
    f32x4 acc[4] = {{0.f,0.f,0.f,0.f},{0.f,0.f,0.f,0.f},{0.f,0.f,0.f,0.f},{0.f,0.f,0.f,0.f}};
#pragma unroll
    for (int s = 0; s < 2; ++s)
#pragma unroll
    for (int t = 0; t < 4; ++t)
        acc[t] = __builtin_amdgcn_mfma_f32_16x16x32_bf16(Af[s].v, Bf[t][s].v, acc[t], 0, 0, 0);

    // ---- fused scores + h store ----
    float av[4], dv[4];
#pragma unroll
    for (int t = 0; t < 4; ++t) { av[t] = a_src[lr + 16*t]; dv[t] = a_dst[lr + 16*t]; }

    float ssv[4], sdv[4];
#pragma unroll
    for (int r = 0; r < 4; ++r) {
        int row = rowbase + 4*lg + r;
        bool ok = row < NN;
        float ps = 0.f, pd = 0.f;
#pragma unroll
        for (int t = 0; t < 4; ++t) {
            float v = acc[t][r];
            ps += v * av[t];
            pd += v * dv[t];
            if (ok) h[(size_t)row * DIM + lr + 16*t] = f2bf(v);
        }
#pragma unroll
        for (int off = 8; off; off >>= 1) {
            ps += __shfl_xor(ps, off, 64);
            pd += __shfl_xor(pd, off, 64);
        }
        ssv[r] = ps; sdv[r] = pd;
    }
    if (lr == 0) {
#pragma unroll
        for (int r = 0; r < 4; ++r) {
            int row = rowbase + 4*lg + r;
            if (row < NN) { s_src[row] = ssv[r]; s_dst[row] = sdv[r]; }
        }
    }
}

// ==================== radix partition, pass 1: histogram ====================
// gcnt is BLOCK-MAJOR [block][bucket]: coalesced writes here, and consumers
// derive prefixes themselves (no separate scan kernel).
__global__ __launch_bounds__(512)
void bin_hist(const int* __restrict__ dst, int* __restrict__ gcnt)
{
    __shared__ int cnt[NBUCK];
    int tid = threadIdx.x;
    for (int i = tid; i < NBUCK; i += 512) cnt[i] = 0;
    __syncthreads();
    int lo = blockIdx.x * BIN_CHUNK;
    int hi = lo + BIN_CHUNK; if (hi > NE) hi = NE;
    for (int e = lo + tid; e < hi; e += 512)
        atomicAdd(&cnt[dst[e] >> BSHIFT], 1);
    __syncthreads();
    for (int i = tid; i < NBUCK; i += 512)
        gcnt[blockIdx.x * NBUCK + i] = cnt[i];
}

// ==================== pass 2 + layer-1 linear, fused by block range ====================
// blocks [0, BIN_BLOCKS): compute own per-bucket window base (prefix over
// earlier blocks' counts, coalesced L2-hot reads), then scatter edges into
// exact bucket-strided windows (LDS cursors only, no global atomics).
// blocks [BIN_BLOCKS, ...): layer-1 MFMA linear (independent of CSR build) --
// latency-bound scatter and MFMA-bound linear co-schedule (r13 A/B: fusion
// is ~5us better than serial).
__global__ __launch_bounds__(512)
void scatter_linear1(const int* __restrict__ src, const int* __restrict__ dst,
                     const float* __restrict__ ea,
                     const int* __restrict__ gcnt,
                     int2* __restrict__ region,
                     const float* __restrict__ x, const float* __restrict__ W1,
                     const float* __restrict__ as1, const float* __restrict__ ad1,
                     bf16_t* __restrict__ h,
                     float* __restrict__ ssrc, float* __restrict__ sdst)
{
    if (blockIdx.x < BIN_BLOCKS) {
        __shared__ int cur[NBUCK];
        int tid = threadIdx.x;
        if (tid < NBUCK) {
            int acc = tid * BCAP;                    // bucket window base
            int m = blockIdx.x;
            for (int j = 0; j < m; ++j)              // exclusive prefix over blocks
                acc += gcnt[j * NBUCK + tid];        // coalesced across tid
            cur[tid] = acc;
        }
        __syncthreads();
        int lo = blockIdx.x * BIN_CHUNK;
        int hi = lo + BIN_CHUNK; if (hi > NE) hi = NE;
        for (int e = lo + tid; e < hi; e += 512) {
            int d = dst[e];
            int b = d >> BSHIFT;
            int pos = atomicAdd(&cur[b], 1);         // LDS atomic only
            region[pos] = make_int2(src[e] | ((d & (BNODES - 1)) << 17),
                                    __float_as_int(ea[e]));
        }
    } else {
        linear_body<false, false>(blockIdx.x - BIN_BLOCKS, x, W1, as1, ad1, h, ssrc, sdst);
    }
}

// ==================== layer-2 linear (standalone, 512 thr) ====================
__global__ __launch_bounds__(512)
void linear2(const void* __restrict__ xin, const float* __restrict__ W,
             const float* __restrict__ a_src, const float* __restrict__ a_dst,
             bf16_t* __restrict__ h, float* __restrict__ s_src, float* __restrict__ s_dst)
{
    linear_body<true, true>(blockIdx.x, xin, W, a_src, a_dst, h, s_src, s_dst);
}

// ==================== stage B: per-bucket CSR build (391 blocks x 256 thr) ====================
// bucket total = column-reduce of gcnt; then count 256 local nodes, wave scan
// (2 barriers), write rowptr/rend, scatter records into the bucket's strided
// csr segment. No global atomics.
__global__ __launch_bounds__(256)
void build_csr(const int* __restrict__ gcnt,
               const int2* __restrict__ region,
               int* __restrict__ rowptr, int* __restrict__ rend,
               int2* __restrict__ csr)
{
    int b    = blockIdx.x;
    int tid  = threadIdx.x;
    int lane = tid & 63;

    // bucket total: each of the 256 threads reads one block's count
    int pv = gcnt[tid * NBUCK + b];
#pragma unroll
    for (int off = 32; off; off >>= 1) pv += __shfl_xor(pv, off, 64);
    __shared__ int wsum[4];
    if ((tid & 63) == 0) wsum[tid >> 6] = pv;
    __syncthreads();
    int cnt = wsum[0] + wsum[1] + wsum[2] + wsum[3];

    const int2* rec = region + (size_t)b * BCAP;

    __shared__ int ncnt[BNODES];
    __shared__ int curs[BNODES];
    __shared__ int wpart[4];
    ncnt[tid] = 0;
    __syncthreads();
    for (int i = tid; i < cnt; i += 256)
        atomicAdd(&ncnt[(rec[i].x >> 17) & (BNODES - 1)], 1);
    __syncthreads();

    int v = ncnt[tid];
    int sc = v;
#pragma unroll
    for (int off = 1; off <= 32; off <<= 1) {
        int t = __shfl_up(sc, off, 64);
        if (lane >= off) sc += t;
    }
    if (lane == 63) wpart[tid >> 6] = sc;
    __syncthreads();
    if (tid == 0) {
        int run = 0;
#pragma unroll
        for (int k = 0; k < 4; ++k) { int t = wpart[k]; wpart[k] = run; run += t; }
    }
    __syncthreads();
    int excl = sc - v + wpart[tid >> 6];
    int base = b * BCAP;

    int node = (b << BSHIFT) + tid;
    if (node < NN) { rowptr[node] = base + excl; rend[node] = base + excl + v; }
    curs[tid] = base + excl;
    __syncthreads();

    for (int i = tid; i < cnt; i += 256) {
        int2 r = rec[i];
        int dl = (r.x >> 17) & (BNODES - 1);
        int pos = atomicAdd(&curs[dl], 1);      // LDS atomic
        csr[pos] = make_int2(r.x & 0x1FFFF, r.y);
    }
}

// ==================== group-per-node single-pass aggregate ====================
// one 16-lane group per dst node (4 nodes/wave). No max-subtraction (scores
// O(10), clamped 60; reference eps inert). Padded lanes carry s=0, w=0.0f ->
// gather loads issue UNCONDITIONALLY (h row 0, L1-hot) and FMAs add exact 0.
// ALL 16 loads issue before any consumption -> one load round-trip per chunk.
template<bool OUT_BF16>
__global__ __launch_bounds__(256)
void fused_agg(const int* __restrict__ rowptr, const int* __restrict__ rend,
               const int2* __restrict__ csr,
               const float* __restrict__ ssrc, const float* __restrict__ sdst,
               const bf16_t* __restrict__ h,
               void* __restrict__ outp)
{
    int tid  = threadIdx.x;
    int lane = tid & 63;
    int wv   = tid >> 6;
    int grp  = lane >> 4;
    int lr   = lane & 15;
    int d    = blockIdx.x * 16 + wv * 4 + grp;
    bool dok = d < NN;

    int rb = 0, deg = 0;
    if (dok) { rb = rowptr[d]; deg = rend[d] - rb; }
    float sdd = dok ? sdst[d] : 0.f;

    // wave-uniform chunk bound
    int wmax = deg;
    wmax = max(wmax, __shfl_xor(wmax, 16, 64));
    wmax = max(wmax, __shfl_xor(wmax, 32, 64));

    float psum = 0.f;
    float ax = 0.f, ay = 0.f, az = 0.f, aw = 0.f;

#define GSWZ(J)                                                                 \
    int   sj##J = __builtin_amdgcn_ds_swizzle(s, (((J) << 5) | 0x10));          \
    float wj##J = __int_as_float(__builtin_amdgcn_ds_swizzle(wbits, (((J) << 5) | 0x10)));
#define GLOAD(J)                                                                \
    ushort4 hv##J = *reinterpret_cast<const ushort4*>(h + (size_t)sj##J * DIM + 4*lr);
#define GACC(J)                                                                 \
    ax += wj##J * bf2f(hv##J.x); ay += wj##J * bf2f(hv##J.y);                   \
    az += wj##J * bf2f(hv##J.z); aw += wj##J * bf2f(hv##J.w);

    for (int cb = 0; cb < wmax; cb += 16) {
        int idx = cb + lr;
        bool v = idx < deg;
        int2 rec = v ? csr[rb + idx] : make_int2(0, 0);
        int   s  = rec.x;
        float a  = ssrc[s] + sdd;
        a = (a >= 0.f) ? a : 0.2f * a;          // leaky relu
        a = fminf(a, 60.f);                     // overflow guard (never hit here)
        float p = v ? __expf(a) : 0.f;
        float w = p * __int_as_float(rec.y);    // exact 0 for padded slots
        int wbits = __float_as_int(w);

        // issue ALL 16 loads back-to-back
        GSWZ(0)  GSWZ(1)  GSWZ(2)  GSWZ(3)  GSWZ(4)  GSWZ(5)  GSWZ(6)  GSWZ(7)
        GSWZ(8)  GSWZ(9)  GSWZ(10) GSWZ(11) GSWZ(12) GSWZ(13) GSWZ(14) GSWZ(15)
        GLOAD(0)  GLOAD(1)  GLOAD(2)  GLOAD(3)  GLOAD(4)  GLOAD(5)  GLOAD(6)  GLOAD(7)
        GLOAD(8)  GLOAD(9)  GLOAD(10) GLOAD(11) GLOAD(12) GLOAD(13) GLOAD(14) GLOAD(15)

        // psum butterfly under the load latency
        float ps = p;
#pragma unroll
        for (int off = 1; off <= 8; off <<= 1) ps += __shfl_xor(ps, off, 64);
        psum += ps;

        GACC(0)  GACC(1)  GACC(2)  GACC(3)  GACC(4)  GACC(5)  GACC(6)  GACC(7)
        GACC(8)  GACC(9)  GACC(10) GACC(11) GACC(12) GACC(13) GACC(14) GACC(15)
    }
#undef GSWZ
#undef GLOAD
#undef GACC

    if (dok) {
        float inv = 1.f / (psum + 1e-16f);
        if (OUT_BF16) {
            ushort4 o;
            o.x = f2bf(ax * inv); o.y = f2bf(ay * inv);
            o.z = f2bf(az * inv); o.w = f2bf(aw * inv);
            *reinterpret_cast<ushort4*>((bf16_t*)outp + (size_t)d * DIM + 4*lr) = o;
        } else {
            float4 o = make_float4(ax * inv, ay * inv, az * inv, aw * inv);
            *reinterpret_cast<float4*>((float*)outp + (size_t)d * DIM + 4*lr) = o;
        }
    }
}

extern "C" void kernel_launch(void* const* d_in, const int* in_sizes, int n_in,
                              void* d_out, int out_size, void* d_ws, size_t ws_size,
                              hipStream_t stream) {
    const float* x   = (const float*)d_in[0];
    const int*   ei  = (const int*)d_in[1];
    const float* ea  = (const float*)d_in[2];
    const float* W1  = (const float*)d_in[3];
    const float* as1 = (const float*)d_in[4];
    const float* ad1 = (const float*)d_in[5];
    const float* W2  = (const float*)d_in[6];
    const float* as2 = (const float*)d_in[7];
    const float* ad2 = (const float*)d_in[8];
    const int* src = ei;            // edge_index[0]
    const int* dst = ei + NE;       // edge_index[1]
    float* out = (float*)d_out;

    // ---- workspace carve-up (~54 MB) ----
    char* p = (char*)d_ws;
    auto carve = [&](size_t bytes) { char* r = p; p += (bytes + 255) & ~(size_t)255; return (void*)r; };
    bf16_t*  acc_bf = (bf16_t*)carve((size_t)NN * DIM * 2);
    bf16_t*  h      = (bf16_t*)carve((size_t)NN * DIM * 2);
    float*   ssrc   = (float*)carve((size_t)NN * 4);
    float*   sdst   = (float*)carve((size_t)NN * 4);
    int*     rowptr = (int*)carve((size_t)NN * 4);
    int*     rend   = (int*)carve((size_t)NN * 4);
    int2*    csr    = (int2*)carve((size_t)NBUCK * BCAP * 8);
    int2*    region = (int2*)carve((size_t)NBUCK * BCAP * 8);
    int*     gcnt   = (int*)carve((size_t)BIN_BLOCKS * NBUCK * 4);
    int*     btot   = (int*)carve((size_t)NBUCK * 4);

    const int GRID_LIN  = (NN + 127) / 128;   // 782 tiles of 128 rows (8 waves)
    const int GRID_NODE = (NN + 15) / 16;     // 6250 blocks, 16 nodes each

    // ---- CSR build + layer-1 linear (fused/overlapped; r13 A/B confirmed) ----
    bin_hist<<<BIN_BLOCKS, 512, 0, stream>>>(dst, gcnt);
    scatter_linear1<<<BIN_BLOCKS + GRID_LIN, 512, 0, stream>>>(
        src, dst, ea, gcnt, region, x, W1, as1, ad1, h, ssrc, sdst);
    build_csr<<<NBUCK, 256, 0, stream>>>(gcnt, region, rowptr, rend, csr);

    // ---- layer 1 aggregate ----
    fused_agg<true><<<GRID_NODE, 256, 0, stream>>>(rowptr, rend, csr, ssrc, sdst, h, acc_bf);

    // ---- layer 2 ----
    linear2<<<GRID_LIN, 512, 0, stream>>>(acc_bf, W2, as2, ad2, h, ssrc, sdst);
    fused_agg<false><<<GRID_NODE, 256, 0, stream>>>(rowptr, rend, csr, ssrc, sdst, h, out);
}

// Round 16
// 129.991 us; speedup vs baseline: 1.2015x; 1.2015x over previous
//
#include <hip/hip_runtime.h>

#define NN 100000
#define NE 1250000
#define DIM 64

#define BSHIFT 8                                   // 256 nodes per bucket
#define BNODES (1 << BSHIFT)
#define NBUCK ((NN + BNODES - 1) / BNODES)         // 391
#define BIN_BLOCKS 256
#define BIN_CHUNK ((NE + BIN_BLOCKS - 1) / BIN_BLOCKS)  // 4883
#define BCAP 4096                                  // fixed per-bucket capacity (avg 3200, ~15 sigma headroom)

typedef unsigned short bf16_t;
typedef __attribute__((ext_vector_type(8))) short short8;
typedef __attribute__((ext_vector_type(8))) unsigned short ushort8;
typedef __attribute__((ext_vector_type(4))) float f32x4;

static __device__ __forceinline__ bf16_t f2bf(float f) {
    union { float f; unsigned int u; } c; c.f = f;
    unsigned int u = c.u;
    u += 0x7FFFu + ((u >> 16) & 1u);          // RNE
    return (bf16_t)(u >> 16);
}
static __device__ __forceinline__ float bf2f(bf16_t b) {
    union { unsigned int u; float f; } c; c.u = ((unsigned int)b) << 16;
    return c.f;
}

union ABFrag { short8 v; short s[8]; };

// ==================== linear via MFMA: h = x @ W^T (+fused scores) ====================
// one wave per 16 rows; 512-thread blocks = 8 waves = 128 rows per tile.
template<bool IN_BF16, bool RELU_IN>
static __device__ __forceinline__
void linear_body(int bid, const void* __restrict__ xin,
                 const float* __restrict__ W,
                 const float* __restrict__ a_src,
                 const float* __restrict__ a_dst,
                 bf16_t* __restrict__ h,
                 float* __restrict__ s_src,
                 float* __restrict__ s_dst)
{
    int tid  = threadIdx.x;
    int lane = tid & 63;
    int wid  = tid >> 6;     // 0..7
    int lr   = lane & 15;    // A-row / B,D-col (mod 16)
    int lg   = lane >> 4;    // k-group / D-row-group
    int rowbase = bid * 128 + wid * 16;

    // ---- B fragments from W (L2-hot, 16 KB) ----
    ABFrag Bf[4][2];
#pragma unroll
    for (int t = 0; t < 4; ++t)
#pragma unroll
    for (int s = 0; s < 2; ++s) {
        const f32x4* wp = reinterpret_cast<const f32x4*>(W + (lr + 16*t)*DIM + 32*s + 8*lg);
        f32x4 w0 = wp[0], w1 = wp[1];
#pragma unroll
        for (int j = 0; j < 4; ++j) {
            Bf[t][s].s[j]     = (short)f2bf(w0[j]);
            Bf[t][s].s[j + 4] = (short)f2bf(w1[j]);
        }
    }

    int arow = rowbase + lr;
    if (arow > NN - 1) arow = NN - 1;        // tail clamp; invalid D-rows masked at store

    // ---- A fragments ----
    ABFrag Af[2];
    if (IN_BF16) {
        const bf16_t* xp = (const bf16_t*)xin + (size_t)arow * DIM + 8*lg;
#pragma unroll
        for (int s = 0; s < 2; ++s) {
            ushort8 xv = *reinterpret_cast<const ushort8*>(xp + 32*s);
#pragma unroll
            for (int j = 0; j < 8; ++j) {
                unsigned short b = xv[j];
                if (RELU_IN) b = (b & 0x8000u) ? (unsigned short)0 : b;   // relu on bf16 bits
                Af[s].s[j] = (short)b;
            }
        }
    } else {
        const float* xp = (const float*)xin + (size_t)arow * DIM + 8*lg;
#pragma unroll
        for (int s = 0; s < 2; ++s) {
            const f32x4* xq = reinterpret_cast<const f32x4*>(xp + 32*s);
            f32x4 x0 = xq[0], x1 = xq[1];
#pragma unroll
            for (int j = 0; j < 4; ++j) {
                float f0 = x0[j], f1 = x1[j];
                if (RELU_IN) { f0 = f0 > 0.f ? f0 : 0.f; f1 = f1 > 0.f ? f1 : 0.f; }
                Af[s].s[j]     = (short)f2bf(f0);
                Af[s].s[j + 4] = (short)f2bf(f1);
            }
        }
    }

    // ---- 8 MFMAs ----
    f32x4 acc[4] = {{0.f,0.f,0.f,0.f},{0.f,0.f,0.f,0.f},{0.f,0.f,0.f,0.f},{0.f,0.f,0.f,0.f}};
#pragma unroll
    for (int s = 0; s < 2; ++s)
#pragma unroll
    for (int t = 0; t < 4; ++t)
        acc[t] = __builtin_amdgcn_mfma_f32_16x16x32_bf16(Af[s].v, Bf[t][s].v, acc[t], 0, 0, 0);

    // ---- fused scores + h store ----
    float av[4], dv[4];
#pragma unroll
    for (int t = 0; t < 4; ++t) { av[t] = a_src[lr + 16*t]; dv[t] = a_dst[lr + 16*t]; }

    float ssv[4], sdv[4];
#pragma unroll
    for (int r = 0; r < 4; ++r) {
        int row = rowbase + 4*lg + r;
        bool ok = row < NN;
        float ps = 0.f, pd = 0.f;
#pragma unroll
        for (int t = 0; t < 4; ++t) {
            float v = acc[t][r];
            ps += v * av[t];
            pd += v * dv[t];
            if (ok) h[(size_t)row * DIM + lr + 16*t] = f2bf(v);
        }
#pragma unroll
        for (int off = 8; off; off >>= 1) {
            ps += __shfl_xor(ps, off, 64);
            pd += __shfl_xor(pd, off, 64);
        }
        ssv[r] = ps; sdv[r] = pd;
    }
    if (lr == 0) {
#pragma unroll
        for (int r = 0; r < 4; ++r) {
            int row = rowbase + 4*lg + r;
            if (row < NN) { s_src[row] = ssv[r]; s_dst[row] = sdv[r]; }
        }
    }
}

// ==================== radix partition, pass 1: histogram ====================
// gcnt bucket-major [bucket][block] (as r12); row_scan turns rows into
// bucket-relative exclusive offsets.
__global__ __launch_bounds__(512)
void bin_hist(const int* __restrict__ dst, int* __restrict__ gcnt)
{
    __shared__ int cnt[NBUCK];
    int tid = threadIdx.x;
    for (int i = tid; i < NBUCK; i += 512) cnt[i] = 0;
    __syncthreads();
    int lo = blockIdx.x * BIN_CHUNK;
    int hi = lo + BIN_CHUNK; if (hi > NE) hi = NE;
    for (int e = lo + tid; e < hi; e += 512)
        atomicAdd(&cnt[dst[e] >> BSHIFT], 1);
    __syncthreads();
    for (int i = tid; i < NBUCK; i += 512)
        gcnt[i * BIN_BLOCKS + blockIdx.x] = cnt[i];
}

// ==================== pass 2: per-bucket row scan (391 blocks x 256 thr) ====================
__global__ __launch_bounds__(256)
void row_scan(int* __restrict__ gcnt, int* __restrict__ btot)
{
    __shared__ int wpart[4];
    int b    = blockIdx.x;
    int tid  = threadIdx.x;
    int lane = tid & 63;
    int v = gcnt[b * BIN_BLOCKS + tid];
    int sc = v;
#pragma unroll
    for (int off = 1; off <= 32; off <<= 1) {
        int t = __shfl_up(sc, off, 64);
        if (lane >= off) sc += t;
    }
    if (lane == 63) wpart[tid >> 6] = sc;
    __syncthreads();
    if (tid == 0) {
        int run = 0;
#pragma unroll
        for (int k = 0; k < 4; ++k) { int t = wpart[k]; wpart[k] = run; run += t; }
    }
    __syncthreads();
    int incl = sc + wpart[tid >> 6];
    gcnt[b * BIN_BLOCKS + tid] = incl - v;       // exclusive, bucket-relative
    if (tid == BIN_BLOCKS - 1) btot[b] = incl;
}

// ==================== pass 3 + layer-1 linear, fused by block range ====================
// scatter blocks: LDS counting-sort the chunk by bucket, then stream out --
// consecutive LDS slots map to consecutive global window slots, so a wave's
// 64 stores span ~4 line-sets instead of ~64 (16x fewer store transactions).
// linear blocks: layer-1 MFMA (independent; r13 A/B showed fusion wins ~5us).
__global__ __launch_bounds__(512)
void scatter_linear1(const int* __restrict__ src, const int* __restrict__ dst,
                     const float* __restrict__ ea,
                     const int* __restrict__ gcnt, const int* __restrict__ btot,
                     int2* __restrict__ region,
                     const float* __restrict__ x, const float* __restrict__ W1,
                     const float* __restrict__ as1, const float* __restrict__ ad1,
                     bf16_t* __restrict__ h,
                     float* __restrict__ ssrc, float* __restrict__ sdst)
{
    if (blockIdx.x < BIN_BLOCKS) {
        __shared__ int2 sbuf[BIN_CHUNK];
        __shared__ unsigned short sbkt[BIN_CHUNK];
        __shared__ int lcur[NBUCK];
        __shared__ int gout[NBUCK];
        __shared__ int wpart[8];
        int tid  = threadIdx.x;
        int lane = tid & 63;
        int blk  = blockIdx.x;

        // per-bucket count for THIS block from row_scan'd gcnt (diff of
        // consecutive exclusive offsets; last block uses btot).
        int cntb = 0, gex = 0;
        if (tid < NBUCK) {
            gex = gcnt[tid * BIN_BLOCKS + blk];
            int nxt = (blk + 1 < BIN_BLOCKS) ? gcnt[tid * BIN_BLOCKS + blk + 1] : btot[tid];
            cntb = nxt - gex;
        }
        // block-local exclusive scan of cntb over buckets (wave scan + wpart)
        int sc = cntb;
#pragma unroll
        for (int off = 1; off <= 32; off <<= 1) {
            int t = __shfl_up(sc, off, 64);
            if (lane >= off) sc += t;
        }
        if (lane == 63) wpart[tid >> 6] = sc;
        __syncthreads();
        if (tid == 0) {
            int run = 0;
#pragma unroll
            for (int k = 0; k < 8; ++k) { int t = wpart[k]; wpart[k] = run; run += t; }
        }
        __syncthreads();
        int excl = sc - cntb + wpart[tid >> 6];
        if (tid < NBUCK) {
            lcur[tid] = excl;
            gout[tid] = tid * BCAP + gex - excl;     // global = gout[b] + local_idx
        }
        __syncthreads();

        int lo = blk * BIN_CHUNK;
        int hi = lo + BIN_CHUNK; if (hi > NE) hi = NE;
        for (int e = lo + tid; e < hi; e += 512) {
            int d = dst[e];
            int b = d >> BSHIFT;
            int pos = atomicAdd(&lcur[b], 1);        // LDS atomic only
            sbuf[pos] = make_int2(src[e] | ((d & (BNODES - 1)) << 17),
                                  __float_as_int(ea[e]));
            sbkt[pos] = (unsigned short)b;
        }
        __syncthreads();

        int T = hi - lo;
        for (int i = tid; i < T; i += 512) {
            int b = sbkt[i];
            region[gout[b] + i] = sbuf[i];           // near-coalesced runs
        }
    } else {
        linear_body<false, false>(blockIdx.x - BIN_BLOCKS, x, W1, as1, ad1, h, ssrc, sdst);
    }
}

// ==================== layer-2 linear (standalone, 512 thr) ====================
__global__ __launch_bounds__(512)
void linear2(const void* __restrict__ xin, const float* __restrict__ W,
             const float* __restrict__ a_src, const float* __restrict__ a_dst,
             bf16_t* __restrict__ h, float* __restrict__ s_src, float* __restrict__ s_dst)
{
    linear_body<true, true>(blockIdx.x, xin, W, a_src, a_dst, h, s_src, s_dst);
}

// ==================== stage B: per-bucket CSR build (391 blocks x 256 thr) ====================
__global__ __launch_bounds__(256)
void build_csr(const int* __restrict__ btot,
               const int2* __restrict__ region,
               int* __restrict__ rowptr, int* __restrict__ rend,
               int2* __restrict__ csr)
{
    int b    = blockIdx.x;
    int tid  = threadIdx.x;
    int lane = tid & 63;
    int cnt  = btot[b];
    const int2* rec = region + (size_t)b * BCAP;

    __shared__ int ncnt[BNODES];
    __shared__ int curs[BNODES];
    __shared__ int wpart[4];
    ncnt[tid] = 0;
    __syncthreads();
    for (int i = tid; i < cnt; i += 256)
        atomicAdd(&ncnt[(rec[i].x >> 17) & (BNODES - 1)], 1);
    __syncthreads();

    int v = ncnt[tid];
    int sc = v;
#pragma unroll
    for (int off = 1; off <= 32; off <<= 1) {
        int t = __shfl_up(sc, off, 64);
        if (lane >= off) sc += t;
    }
    if (lane == 63) wpart[tid >> 6] = sc;
    __syncthreads();
    if (tid == 0) {
        int run = 0;
#pragma unroll
        for (int k = 0; k < 4; ++k) { int t = wpart[k]; wpart[k] = run; run += t; }
    }
    __syncthreads();
    int excl = sc - v + wpart[tid >> 6];
    int base = b * BCAP;

    int node = (b << BSHIFT) + tid;
    if (node < NN) { rowptr[node] = base + excl; rend[node] = base + excl + v; }
    curs[tid] = base + excl;
    __syncthreads();

    for (int i = tid; i < cnt; i += 256) {
        int2 r = rec[i];
        int dl = (r.x >> 17) & (BNODES - 1);
        int pos = atomicAdd(&curs[dl], 1);      // LDS atomic
        csr[pos] = make_int2(r.x & 0x1FFFF, r.y);
    }
}

// ==================== group-per-node single-pass aggregate ====================
// one 16-lane group per dst node (4 nodes/wave). No max-subtraction (scores
// O(10), clamped 60; reference eps inert). Padded lanes carry s=0, w=0.0f ->
// gather loads issue UNCONDITIONALLY (h row 0, L1-hot) and FMAs add exact 0.
// ALL 16 loads issue before any consumption -> one load round-trip per chunk.
template<bool OUT_BF16>
__global__ __launch_bounds__(256)
void fused_agg(const int* __restrict__ rowptr, const int* __restrict__ rend,
               const int2* __restrict__ csr,
               const float* __restrict__ ssrc, const float* __restrict__ sdst,
               const bf16_t* __restrict__ h,
               void* __restrict__ outp)
{
    int tid  = threadIdx.x;
    int lane = tid & 63;
    int wv   = tid >> 6;
    int grp  = lane >> 4;
    int lr   = lane & 15;
    int d    = blockIdx.x * 16 + wv * 4 + grp;
    bool dok = d < NN;

    int rb = 0, deg = 0;
    if (dok) { rb = rowptr[d]; deg = rend[d] - rb; }
    float sdd = dok ? sdst[d] : 0.f;

    // wave-uniform chunk bound
    int wmax = deg;
    wmax = max(wmax, __shfl_xor(wmax, 16, 64));
    wmax = max(wmax, __shfl_xor(wmax, 32, 64));

    float psum = 0.f;
    float ax = 0.f, ay = 0.f, az = 0.f, aw = 0.f;

#define GSWZ(J)                                                                 \
    int   sj##J = __builtin_amdgcn_ds_swizzle(s, (((J) << 5) | 0x10));          \
    float wj##J = __int_as_float(__builtin_amdgcn_ds_swizzle(wbits, (((J) << 5) | 0x10)));
#define GLOAD(J)                                                                \
    ushort4 hv##J = *reinterpret_cast<const ushort4*>(h + (size_t)sj##J * DIM + 4*lr);
#define GACC(J)                                                                 \
    ax += wj##J * bf2f(hv##J.x); ay += wj##J * bf2f(hv##J.y);                   \
    az += wj##J * bf2f(hv##J.z); aw += wj##J * bf2f(hv##J.w);

    for (int cb = 0; cb < wmax; cb += 16) {
        int idx = cb + lr;
        bool v = idx < deg;
        int2 rec = v ? csr[rb + idx] : make_int2(0, 0);
        int   s  = rec.x;
        float a  = ssrc[s] + sdd;
        a = (a >= 0.f) ? a : 0.2f * a;          // leaky relu
        a = fminf(a, 60.f);                     // overflow guard (never hit here)
        float p = v ? __expf(a) : 0.f;
        float w = p * __int_as_float(rec.y);    // exact 0 for padded slots
        int wbits = __float_as_int(w);

        // issue ALL 16 loads back-to-back
        GSWZ(0)  GSWZ(1)  GSWZ(2)  GSWZ(3)  GSWZ(4)  GSWZ(5)  GSWZ(6)  GSWZ(7)
        GSWZ(8)  GSWZ(9)  GSWZ(10) GSWZ(11) GSWZ(12) GSWZ(13) GSWZ(14) GSWZ(15)
        GLOAD(0)  GLOAD(1)  GLOAD(2)  GLOAD(3)  GLOAD(4)  GLOAD(5)  GLOAD(6)  GLOAD(7)
        GLOAD(8)  GLOAD(9)  GLOAD(10) GLOAD(11) GLOAD(12) GLOAD(13) GLOAD(14) GLOAD(15)

        // psum butterfly under the load latency
        float ps = p;
#pragma unroll
        for (int off = 1; off <= 8; off <<= 1) ps += __shfl_xor(ps, off, 64);
        psum += ps;

        GACC(0)  GACC(1)  GACC(2)  GACC(3)  GACC(4)  GACC(5)  GACC(6)  GACC(7)
        GACC(8)  GACC(9)  GACC(10) GACC(11) GACC(12) GACC(13) GACC(14) GACC(15)
    }
#undef GSWZ
#undef GLOAD
#undef GACC

    if (dok) {
        float inv = 1.f / (psum + 1e-16f);
        if (OUT_BF16) {
            ushort4 o;
            o.x = f2bf(ax * inv); o.y = f2bf(ay * inv);
            o.z = f2bf(az * inv); o.w = f2bf(aw * inv);
            *reinterpret_cast<ushort4*>((bf16_t*)outp + (size_t)d * DIM + 4*lr) = o;
        } else {
            float4 o = make_float4(ax * inv, ay * inv, az * inv, aw * inv);
            *reinterpret_cast<float4*>((float*)outp + (size_t)d * DIM + 4*lr) = o;
        }
    }
}

extern "C" void kernel_launch(void* const* d_in, const int* in_sizes, int n_in,
                              void* d_out, int out_size, void* d_ws, size_t ws_size,
                              hipStream_t stream) {
    const float* x   = (const float*)d_in[0];
    const int*   ei  = (const int*)d_in[1];
    const float* ea  = (const float*)d_in[2];
    const float* W1  = (const float*)d_in[3];
    const float* as1 = (const float*)d_in[4];
    const float* ad1 = (const float*)d_in[5];
    const float* W2  = (const float*)d_in[6];
    const float* as2 = (const float*)d_in[7];
    const float* ad2 = (const float*)d_in[8];
    const int* src = ei;            // edge_index[0]
    const int* dst = ei + NE;       // edge_index[1]
    float* out = (float*)d_out;

    // ---- workspace carve-up (~54 MB) ----
    char* p = (char*)d_ws;
    auto carve = [&](size_t bytes) { char* r = p; p += (bytes + 255) & ~(size_t)255; return (void*)r; };
    bf16_t*  acc_bf = (bf16_t*)carve((size_t)NN * DIM * 2);
    bf16_t*  h      = (bf16_t*)carve((size_t)NN * DIM * 2);
    float*   ssrc   = (float*)carve((size_t)NN * 4);
    float*   sdst   = (float*)carve((size_t)NN * 4);
    int*     rowptr = (int*)carve((size_t)NN * 4);
    int*     rend   = (int*)carve((size_t)NN * 4);
    int2*    csr    = (int2*)carve((size_t)NBUCK * BCAP * 8);
    int2*    region = (int2*)carve((size_t)NBUCK * BCAP * 8);
    int*     gcnt   = (int*)carve((size_t)NBUCK * BIN_BLOCKS * 4);
    int*     btot   = (int*)carve((size_t)NBUCK * 4);

    const int GRID_LIN  = (NN + 127) / 128;   // 782 tiles of 128 rows (8 waves)
    const int GRID_NODE = (NN + 15) / 16;     // 6250 blocks, 16 nodes each

    // ---- CSR build + layer-1 linear (fused/overlapped; r13 A/B confirmed) ----
    bin_hist<<<BIN_BLOCKS, 512, 0, stream>>>(dst, gcnt);
    row_scan<<<NBUCK, 256, 0, stream>>>(gcnt, btot);
    scatter_linear1<<<BIN_BLOCKS + GRID_LIN, 512, 0, stream>>>(
        src, dst, ea, gcnt, btot, region, x, W1, as1, ad1, h, ssrc, sdst);
    build_csr<<<NBUCK, 256, 0, stream>>>(btot, region, rowptr, rend, csr);

    // ---- layer 1 aggregate ----
    fused_agg<true><<<GRID_NODE, 256, 0, stream>>>(rowptr, rend, csr, ssrc, sdst, h, acc_bf);

    // ---- layer 2 ----
    linear2<<<GRID_LIN, 512, 0, stream>>>(acc_bf, W2, as2, ad2, h, ssrc, sdst);
    fused_agg<false><<<GRID_NODE, 256, 0, stream>>>(rowptr, rend, csr, ssrc, sdst, h, out);
}

// Round 17
// 119.386 us; speedup vs baseline: 1.3083x; 1.0888x over previous
//
#include <hip/hip_runtime.h>

#define NN 100000
#define NE 1250000
#define DIM 64

#define BSHIFT 8                                   // 256 nodes per bucket
#define BNODES (1 << BSHIFT)
#define NBUCK ((NN + BNODES - 1) / BNODES)         // 391
#define BIN_BLOCKS 256
#define BIN_CHUNK ((NE + BIN_BLOCKS - 1) / BIN_BLOCKS)  // 4883
#define BCAP 4096                                  // fixed per-bucket capacity (avg 3200, ~15 sigma headroom)

typedef unsigned short bf16_t;
typedef __attribute__((ext_vector_type(8))) short short8;
typedef __attribute__((ext_vector_type(8))) unsigned short ushort8;
typedef __attribute__((ext_vector_type(4))) float f32x4;

static __device__ __forceinline__ bf16_t f2bf(float f) {
    union { float f; unsigned int u; } c; c.f = f;
    unsigned int u = c.u;
    u += 0x7FFFu + ((u >> 16) & 1u);          // RNE
    return (bf16_t)(u >> 16);
}
static __device__ __forceinline__ float bf2f(bf16_t b) {
    union { unsigned int u; float f; } c; c.u = ((unsigned int)b) << 16;
    return c.f;
}

union ABFrag { short8 v; short s[8]; };

// ==================== linear via MFMA: h = x @ W^T (+fused scores) ====================
// one wave per 16 rows; 512-thread blocks = 8 waves = 128 rows per tile.
template<bool IN_BF16, bool RELU_IN>
static __device__ __forceinline__
void linear_body(int bid, const void* __restrict__ xin,
                 const float* __restrict__ W,
                 const float* __restrict__ a_src,
                 const float* __restrict__ a_dst,
                 bf16_t* __restrict__ h,
                 float* __restrict__ s_src,
                 float* __restrict__ s_dst)
{
    int tid  = threadIdx.x;
    int lane = tid & 63;
    int wid  = tid >> 6;     // 0..7
    int lr   = lane & 15;    // A-row / B,D-col (mod 16)
    int lg   = lane >> 4;    // k-group / D-row-group
    int rowbase = bid * 128 + wid * 16;

    // ---- B fragments from W (L2-hot, 16 KB) ----
    ABFrag Bf[4][2];
#pragma unroll
    for (int t = 0; t < 4; ++t)
#pragma unroll
    for (int s = 0; s < 2; ++s) {
        const f32x4* wp = reinterpret_cast<const f32x4*>(W + (lr + 16*t)*DIM + 32*s + 8*lg);
        f32x4 w0 = wp[0], w1 = wp[1];
#pragma unroll
        for (int j = 0; j < 4; ++j) {
            Bf[t][s].s[j]     = (short)f2bf(w0[j]);
            Bf[t][s].s[j + 4] = (short)f2bf(w1[j]);
        }
    }

    int arow = rowbase + lr;
    if (arow > NN - 1) arow = NN - 1;        // tail clamp; invalid D-rows masked at store

    // ---- A fragments ----
    ABFrag Af[2];
    if (IN_BF16) {
        const bf16_t* xp = (const bf16_t*)xin + (size_t)arow * DIM + 8*lg;
#pragma unroll
        for (int s = 0; s < 2; ++s) {
            ushort8 xv = *reinterpret_cast<const ushort8*>(xp + 32*s);
#pragma unroll
            for (int j = 0; j < 8; ++j) {
                unsigned short b = xv[j];
                if (RELU_IN) b = (b & 0x8000u) ? (unsigned short)0 : b;   // relu on bf16 bits
                Af[s].s[j] = (short)b;
            }
        }
    } else {
        const float* xp = (const float*)xin + (size_t)arow * DIM + 8*lg;
#pragma unroll
        for (int s = 0; s < 2; ++s) {
            const f32x4* xq = reinterpret_cast<const f32x4*>(xp + 32*s);
            f32x4 x0 = xq[0], x1 = xq[1];
#pragma unroll
            for (int j = 0; j < 4; ++j) {
                float f0 = x0[j], f1 = x1[j];
                if (RELU_IN) { f0 = f0 > 0.f ? f0 : 0.f; f1 = f1 > 0.f ? f1 : 0.f; }
                Af[s].s[j]     = (short)f2bf(f0);
                Af[s].s[j + 4] = (short)f2bf(f1);
            }
        }
    }

    // ---- 8 MFMAs ----
    f32x4 acc[4] = {{0.f,0.f,0.f,0.f},{0.f,0.f,0.f,0.f},{0.f,0.f,0.f,0.f},{0.f,0.f,0.f,0.f}};
#pragma unroll
    for (int s = 0; s < 2; ++s)
#pragma unroll
    for (int t = 0; t < 4; ++t)
        acc[t] = __builtin_amdgcn_mfma_f32_16x16x32_bf16(Af[s].v, Bf[t][s].v, acc[t], 0, 0, 0);

    // ---- fused scores + h store ----
    float av[4], dv[4];
#pragma unroll
    for (int t = 0; t < 4; ++t) { av[t] = a_src[lr + 16*t]; dv[t] = a_dst[lr + 16*t]; }

    float ssv[4], sdv[4];
#pragma unroll
    for (int r = 0; r < 4; ++r) {
        int row = rowbase + 4*lg + r;
        bool ok = row < NN;
        float ps = 0.f, pd = 0.f;
#pragma unroll
        for (int t = 0; t < 4; ++t) {
            float v = acc[t][r];
            ps += v * av[t];
            pd += v * dv[t];
            if (ok) h[(size_t)row * DIM + lr + 16*t] = f2bf(v);
        }
#pragma unroll
        for (int off = 8; off; off >>= 1) {
            ps += __shfl_xor(ps, off, 64);
            pd += __shfl_xor(pd, off, 64);
        }
        ssv[r] = ps; sdv[r] = pd;
    }
    if (lr == 0) {
#pragma unroll
        for (int r = 0; r < 4; ++r) {
            int row = rowbase + 4*lg + r;
            if (row < NN) { s_src[row] = ssv[r]; s_dst[row] = sdv[r]; }
        }
    }
}

// ==================== radix partition, pass 1: histogram ====================
__global__ __launch_bounds__(512)
void bin_hist(const int* __restrict__ dst, int* __restrict__ gcnt)
{
    __shared__ int cnt[NBUCK];
    int tid = threadIdx.x;
    for (int i = tid; i < NBUCK; i += 512) cnt[i] = 0;
    __syncthreads();
    int lo = blockIdx.x * BIN_CHUNK;
    int hi = lo + BIN_CHUNK; if (hi > NE) hi = NE;
    for (int e = lo + tid; e < hi; e += 512)
        atomicAdd(&cnt[dst[e] >> BSHIFT], 1);
    __syncthreads();
    for (int i = tid; i < NBUCK; i += 512)
        gcnt[i * BIN_BLOCKS + blockIdx.x] = cnt[i];
}

// ==================== pass 2: per-bucket row scan (391 blocks x 256 thr) ====================
__global__ __launch_bounds__(256)
void row_scan(int* __restrict__ gcnt, int* __restrict__ btot)
{
    __shared__ int wpart[4];
    int b    = blockIdx.x;
    int tid  = threadIdx.x;
    int lane = tid & 63;
    int v = gcnt[b * BIN_BLOCKS + tid];
    int sc = v;
#pragma unroll
    for (int off = 1; off <= 32; off <<= 1) {
        int t = __shfl_up(sc, off, 64);
        if (lane >= off) sc += t;
    }
    if (lane == 63) wpart[tid >> 6] = sc;
    __syncthreads();
    if (tid == 0) {
        int run = 0;
#pragma unroll
        for (int k = 0; k < 4; ++k) { int t = wpart[k]; wpart[k] = run; run += t; }
    }
    __syncthreads();
    int incl = sc + wpart[tid >> 6];
    gcnt[b * BIN_BLOCKS + tid] = incl - v;       // exclusive, bucket-relative
    if (tid == BIN_BLOCKS - 1) btot[b] = incl;
}

// ==================== pass 3 + layer-1 linear, fused by block range ====================
// scatter blocks: LDS counting-sort the chunk by bucket, then stream out --
// consecutive LDS slots map to consecutive global window slots (r15: -3us).
// linear blocks: layer-1 MFMA (independent; r13 A/B showed fusion wins ~5us).
__global__ __launch_bounds__(512)
void scatter_linear1(const int* __restrict__ src, const int* __restrict__ dst,
                     const float* __restrict__ ea,
                     const int* __restrict__ gcnt, const int* __restrict__ btot,
                     int2* __restrict__ region,
                     const float* __restrict__ x, const float* __restrict__ W1,
                     const float* __restrict__ as1, const float* __restrict__ ad1,
                     bf16_t* __restrict__ h,
                     float* __restrict__ ssrc, float* __restrict__ sdst)
{
    if (blockIdx.x < BIN_BLOCKS) {
        __shared__ int2 sbuf[BIN_CHUNK];
        __shared__ unsigned short sbkt[BIN_CHUNK];
        __shared__ int lcur[NBUCK];
        __shared__ int gout[NBUCK];
        __shared__ int wpart[8];
        int tid  = threadIdx.x;
        int lane = tid & 63;
        int blk  = blockIdx.x;

        int cntb = 0, gex = 0;
        if (tid < NBUCK) {
            gex = gcnt[tid * BIN_BLOCKS + blk];
            int nxt = (blk + 1 < BIN_BLOCKS) ? gcnt[tid * BIN_BLOCKS + blk + 1] : btot[tid];
            cntb = nxt - gex;
        }
        int sc = cntb;
#pragma unroll
        for (int off = 1; off <= 32; off <<= 1) {
            int t = __shfl_up(sc, off, 64);
            if (lane >= off) sc += t;
        }
        if (lane == 63) wpart[tid >> 6] = sc;
        __syncthreads();
        if (tid == 0) {
            int run = 0;
#pragma unroll
            for (int k = 0; k < 8; ++k) { int t = wpart[k]; wpart[k] = run; run += t; }
        }
        __syncthreads();
        int excl = sc - cntb + wpart[tid >> 6];
        if (tid < NBUCK) {
            lcur[tid] = excl;
            gout[tid] = tid * BCAP + gex - excl;     // global = gout[b] + local_idx
        }
        __syncthreads();

        int lo = blk * BIN_CHUNK;
        int hi = lo + BIN_CHUNK; if (hi > NE) hi = NE;
        for (int e = lo + tid; e < hi; e += 512) {
            int d = dst[e];
            int b = d >> BSHIFT;
            int pos = atomicAdd(&lcur[b], 1);        // LDS atomic only
            sbuf[pos] = make_int2(src[e] | ((d & (BNODES - 1)) << 17),
                                  __float_as_int(ea[e]));
            sbkt[pos] = (unsigned short)b;
        }
        __syncthreads();

        int T = hi - lo;
        for (int i = tid; i < T; i += 512) {
            int b = sbkt[i];
            region[gout[b] + i] = sbuf[i];           // near-coalesced runs
        }
    } else {
        linear_body<false, false>(blockIdx.x - BIN_BLOCKS, x, W1, as1, ad1, h, ssrc, sdst);
    }
}

// ==================== stage B: per-bucket CSR build (391 blocks x 256 thr) ====================
__global__ __launch_bounds__(256)
void build_csr(const int* __restrict__ btot,
               const int2* __restrict__ region,
               int* __restrict__ rowptr, int* __restrict__ rend,
               int2* __restrict__ csr)
{
    int b    = blockIdx.x;
    int tid  = threadIdx.x;
    int lane = tid & 63;
    int cnt  = btot[b];
    const int2* rec = region + (size_t)b * BCAP;

    __shared__ int ncnt[BNODES];
    __shared__ int curs[BNODES];
    __shared__ int wpart[4];
    ncnt[tid] = 0;
    __syncthreads();
    for (int i = tid; i < cnt; i += 256)
        atomicAdd(&ncnt[(rec[i].x >> 17) & (BNODES - 1)], 1);
    __syncthreads();

    int v = ncnt[tid];
    int sc = v;
#pragma unroll
    for (int off = 1; off <= 32; off <<= 1) {
        int t = __shfl_up(sc, off, 64);
        if (lane >= off) sc += t;
    }
    if (lane == 63) wpart[tid >> 6] = sc;
    __syncthreads();
    if (tid == 0) {
        int run = 0;
#pragma unroll
        for (int k = 0; k < 4; ++k) { int t = wpart[k]; wpart[k] = run; run += t; }
    }
    __syncthreads();
    int excl = sc - v + wpart[tid >> 6];
    int base = b * BCAP;

    int node = (b << BSHIFT) + tid;
    if (node < NN) { rowptr[node] = base + excl; rend[node] = base + excl + v; }
    curs[tid] = base + excl;
    __syncthreads();

    for (int i = tid; i < cnt; i += 256) {
        int2 r = rec[i];
        int dl = (r.x >> 17) & (BNODES - 1);
        int pos = atomicAdd(&curs[dl], 1);      // LDS atomic
        csr[pos] = make_int2(r.x & 0x1FFFF, r.y);
    }
}

// ==================== group-per-node single-pass aggregate (+optional fused layer-2 linear) ====================
// one 16-lane group per dst node (4 nodes/wave; 16 nodes/block). Gather as r15.
// FUSE_LIN2: block's 16 normalized+relu'd rows = one MFMA M-tile -> write to
// LDS (stride 72 bf16 to dodge the 128B-stride bank conflict), then wave wv
// computes column-tile t=wv of h2 = relu(acc)@W2^T (2 MFMAs) + fused scores
// (cross-wave reduce via LDS). Deletes the acc roundtrip + linear2 dispatch.
// relu/bf16-round commute -> h2 bit-identical to the unfused path.
template<bool FUSE_LIN2>
__global__ __launch_bounds__(256)
void fused_agg(const int* __restrict__ rowptr, const int* __restrict__ rend,
               const int2* __restrict__ csr,
               const float* __restrict__ ssrc, const float* __restrict__ sdst,
               const bf16_t* __restrict__ h,
               const float* __restrict__ W2, const float* __restrict__ as2,
               const float* __restrict__ ad2,
               bf16_t* __restrict__ h2, float* __restrict__ ssrc2,
               float* __restrict__ sdst2,
               float* __restrict__ outp)
{
    __shared__ bf16_t rowbuf[16][72];
    __shared__ float sps[4][16], spd[4][16];

    int tid  = threadIdx.x;
    int lane = tid & 63;
    int wv   = tid >> 6;
    int grp  = lane >> 4;
    int lr   = lane & 15;
    int d    = blockIdx.x * 16 + wv * 4 + grp;
    bool dok = d < NN;

    int rb = 0, deg = 0;
    if (dok) { rb = rowptr[d]; deg = rend[d] - rb; }
    float sdd = dok ? sdst[d] : 0.f;

    // wave-uniform chunk bound
    int wmax = deg;
    wmax = max(wmax, __shfl_xor(wmax, 16, 64));
    wmax = max(wmax, __shfl_xor(wmax, 32, 64));

    float psum = 0.f;
    float ax = 0.f, ay = 0.f, az = 0.f, aw = 0.f;

#define GSWZ(J)                                                                 \
    int   sj##J = __builtin_amdgcn_ds_swizzle(s, (((J) << 5) | 0x10));          \
    float wj##J = __int_as_float(__builtin_amdgcn_ds_swizzle(wbits, (((J) << 5) | 0x10)));
#define GLOAD(J)                                                                \
    ushort4 hv##J = *reinterpret_cast<const ushort4*>(h + (size_t)sj##J * DIM + 4*lr);
#define GACC(J)                                                                 \
    ax += wj##J * bf2f(hv##J.x); ay += wj##J * bf2f(hv##J.y);                   \
    az += wj##J * bf2f(hv##J.z); aw += wj##J * bf2f(hv##J.w);

    for (int cb = 0; cb < wmax; cb += 16) {
        int idx = cb + lr;
        bool v = idx < deg;
        int2 rec = v ? csr[rb + idx] : make_int2(0, 0);
        int   s  = rec.x;
        float a  = ssrc[s] + sdd;
        a = (a >= 0.f) ? a : 0.2f * a;          // leaky relu
        a = fminf(a, 60.f);                     // overflow guard (never hit here)
        float p = v ? __expf(a) : 0.f;
        float w = p * __int_as_float(rec.y);    // exact 0 for padded slots
        int wbits = __float_as_int(w);

        GSWZ(0)  GSWZ(1)  GSWZ(2)  GSWZ(3)  GSWZ(4)  GSWZ(5)  GSWZ(6)  GSWZ(7)
        GSWZ(8)  GSWZ(9)  GSWZ(10) GSWZ(11) GSWZ(12) GSWZ(13) GSWZ(14) GSWZ(15)
        GLOAD(0)  GLOAD(1)  GLOAD(2)  GLOAD(3)  GLOAD(4)  GLOAD(5)  GLOAD(6)  GLOAD(7)
        GLOAD(8)  GLOAD(9)  GLOAD(10) GLOAD(11) GLOAD(12) GLOAD(13) GLOAD(14) GLOAD(15)

        float ps = p;
#pragma unroll
        for (int off = 1; off <= 8; off <<= 1) ps += __shfl_xor(ps, off, 64);
        psum += ps;

        GACC(0)  GACC(1)  GACC(2)  GACC(3)  GACC(4)  GACC(5)  GACC(6)  GACC(7)
        GACC(8)  GACC(9)  GACC(10) GACC(11) GACC(12) GACC(13) GACC(14) GACC(15)
    }
#undef GSWZ
#undef GLOAD
#undef GACC

    if (!FUSE_LIN2) {
        if (dok) {
            float inv = 1.f / (psum + 1e-16f);
            float4 o = make_float4(ax * inv, ay * inv, az * inv, aw * inv);
            *reinterpret_cast<float4*>(outp + (size_t)d * DIM + 4*lr) = o;
        }
        return;
    }

    // ---- fused layer-2 linear epilogue ----
    {
        float inv = dok ? 1.f / (psum + 1e-16f) : 0.f;
        float r0 = ax * inv, r1 = ay * inv, r2 = az * inv, r3 = aw * inv;
        r0 = r0 > 0.f ? r0 : 0.f;  r1 = r1 > 0.f ? r1 : 0.f;   // relu
        r2 = r2 > 0.f ? r2 : 0.f;  r3 = r3 > 0.f ? r3 : 0.f;
        int ns = wv * 4 + grp;
        ushort4 pk;
        pk.x = f2bf(r0); pk.y = f2bf(r1); pk.z = f2bf(r2); pk.w = f2bf(r3);
        *reinterpret_cast<ushort4*>(&rowbuf[ns][4 * lr]) = pk;
    }
    __syncthreads();

    int lg = lane >> 4;   // k-group for the MFMA (same bits as grp)
    // A fragments from rowbuf (row = lr = node slot)
    ABFrag Af2[2];
#pragma unroll
    for (int s = 0; s < 2; ++s)
        Af2[s].v = *reinterpret_cast<const short8*>(&rowbuf[lr][32 * s + 8 * lg]);
    // B fragments: wave wv owns column tile t=wv
    ABFrag Bf2[2];
#pragma unroll
    for (int s = 0; s < 2; ++s) {
        const f32x4* wp = reinterpret_cast<const f32x4*>(W2 + (lr + 16 * wv) * DIM + 32 * s + 8 * lg);
        f32x4 w0 = wp[0], w1 = wp[1];
#pragma unroll
        for (int j = 0; j < 4; ++j) {
            Bf2[s].s[j]     = (short)f2bf(w0[j]);
            Bf2[s].s[j + 4] = (short)f2bf(w1[j]);
        }
    }
    f32x4 a2 = {0.f, 0.f, 0.f, 0.f};
    a2 = __builtin_amdgcn_mfma_f32_16x16x32_bf16(Af2[0].v, Bf2[0].v, a2, 0, 0, 0);
    a2 = __builtin_amdgcn_mfma_f32_16x16x32_bf16(Af2[1].v, Bf2[1].v, a2, 0, 0, 0);

    float av = as2[lr + 16 * wv], dv = ad2[lr + 16 * wv];
#pragma unroll
    for (int r = 0; r < 4; ++r) {
        int ns = 4 * lg + r;
        int node = blockIdx.x * 16 + ns;
        if (node < NN) h2[(size_t)node * DIM + lr + 16 * wv] = f2bf(a2[r]);
        float cs = a2[r] * av, cd = a2[r] * dv;
#pragma unroll
        for (int off = 8; off; off >>= 1) {
            cs += __shfl_xor(cs, off, 64);
            cd += __shfl_xor(cd, off, 64);
        }
        if (lr == 0) { sps[wv][ns] = cs; spd[wv][ns] = cd; }
    }
    __syncthreads();
    if (tid < 16) {
        int node = blockIdx.x * 16 + tid;
        if (node < NN) {
            ssrc2[node] = sps[0][tid] + sps[1][tid] + sps[2][tid] + sps[3][tid];
            sdst2[node] = spd[0][tid] + spd[1][tid] + spd[2][tid] + spd[3][tid];
        }
    }
}

extern "C" void kernel_launch(void* const* d_in, const int* in_sizes, int n_in,
                              void* d_out, int out_size, void* d_ws, size_t ws_size,
                              hipStream_t stream) {
    const float* x   = (const float*)d_in[0];
    const int*   ei  = (const int*)d_in[1];
    const float* ea  = (const float*)d_in[2];
    const float* W1  = (const float*)d_in[3];
    const float* as1 = (const float*)d_in[4];
    const float* ad1 = (const float*)d_in[5];
    const float* W2  = (const float*)d_in[6];
    const float* as2 = (const float*)d_in[7];
    const float* ad2 = (const float*)d_in[8];
    const int* src = ei;            // edge_index[0]
    const int* dst = ei + NE;       // edge_index[1]
    float* out = (float*)d_out;

    // ---- workspace carve-up (~54 MB) ----
    char* p = (char*)d_ws;
    auto carve = [&](size_t bytes) { char* r = p; p += (bytes + 255) & ~(size_t)255; return (void*)r; };
    bf16_t*  h2     = (bf16_t*)carve((size_t)NN * DIM * 2);
    bf16_t*  h      = (bf16_t*)carve((size_t)NN * DIM * 2);
    float*   ssrc   = (float*)carve((size_t)NN * 4);
    float*   sdst   = (float*)carve((size_t)NN * 4);
    float*   ssrc2  = (float*)carve((size_t)NN * 4);
    float*   sdst2  = (float*)carve((size_t)NN * 4);
    int*     rowptr = (int*)carve((size_t)NN * 4);
    int*     rend   = (int*)carve((size_t)NN * 4);
    int2*    csr    = (int2*)carve((size_t)NBUCK * BCAP * 8);
    int2*    region = (int2*)carve((size_t)NBUCK * BCAP * 8);
    int*     gcnt   = (int*)carve((size_t)NBUCK * BIN_BLOCKS * 4);
    int*     btot   = (int*)carve((size_t)NBUCK * 4);

    const int GRID_LIN  = (NN + 127) / 128;   // 782 tiles of 128 rows (8 waves)
    const int GRID_NODE = (NN + 15) / 16;     // 6250 blocks, 16 nodes each

    // ---- CSR build + layer-1 linear (fused/overlapped; r13 A/B confirmed) ----
    bin_hist<<<BIN_BLOCKS, 512, 0, stream>>>(dst, gcnt);
    row_scan<<<NBUCK, 256, 0, stream>>>(gcnt, btot);
    scatter_linear1<<<BIN_BLOCKS + GRID_LIN, 512, 0, stream>>>(
        src, dst, ea, gcnt, btot, region, x, W1, as1, ad1, h, ssrc, sdst);
    build_csr<<<NBUCK, 256, 0, stream>>>(btot, region, rowptr, rend, csr);

    // ---- layer-1 aggregate + fused layer-2 linear ----
    fused_agg<true><<<GRID_NODE, 256, 0, stream>>>(
        rowptr, rend, csr, ssrc, sdst, h, W2, as2, ad2, h2, ssrc2, sdst2, nullptr);

    // ---- layer-2 aggregate ----
    fused_agg<false><<<GRID_NODE, 256, 0, stream>>>(
        rowptr, rend, csr, ssrc2, sdst2, h2, nullptr, nullptr, nullptr,
        nullptr, nullptr, nullptr, out);
}